// Round 2
// baseline (163.512 us; speedup 1.0000x reference)
//
#include <hip/hip_runtime.h>
#include <math.h>

#define B 8
#define C 512
#define L 8192
#define CS 16
#define N 512      // L/CS chunk steps
#define C8 64      // C/8 bottleneck dim
#define SEG 16     // EMA scan segments per row
#define SL 32      // N/SEG steps per segment

// ---------------------------------------------------------------------------
// Kernel 1: chunked average pooling.  x [B,C,L] -> pool [B,N,C]
// 4 threads per chunk, each loads one float4 (fully coalesced read).
// ---------------------------------------------------------------------------
__global__ __launch_bounds__(256) void pool_k(const float* __restrict__ x,
                                              float* __restrict__ pool) {
    const int id = blockIdx.x * 256 + threadIdx.x;      // B*C*L/4 threads
    const int q = id & 3;
    const int chunk = id >> 2;                          // (b*C + c)*N + n
    const int n = chunk & (N - 1);
    const int bc = chunk >> 9;
    const int c = bc & (C - 1);
    const int b = bc >> 9;

    const float4 v = reinterpret_cast<const float4*>(x)[id];
    float s = v.x + v.y + v.z + v.w;
    s += __shfl_down(s, 1, 4);
    s += __shfl_down(s, 2, 4);
    if (q == 0) {
        pool[((size_t)b * N + n) * C + c] = s * (1.0f / 16.0f);
    }
}

// ---------------------------------------------------------------------------
// Kernel 2: EMA pass A — segment-local scans + per-segment carry.
// Thread per (b, s, c): scans its 32-chunk segment from y=0, overwrites pool
// with local values, writes final local y to carry[b][s][c].
// Also folds in the (tiny) weight re-pack for the SE matvecs:
//   w1 [C8][C] -> w1t4 float4-interleaved [(k/4)*C8 + o][4]
//   w2 [C][C8] -> w2t4 float4-interleaved [(k/4)*C  + c][4]
// ---------------------------------------------------------------------------
__global__ __launch_bounds__(256) void emaA_k(const float* __restrict__ gamma,
                                              float* __restrict__ pool,
                                              float* __restrict__ carry,
                                              const float* __restrict__ w1,
                                              const float* __restrict__ w2,
                                              float* __restrict__ w1t4,
                                              float* __restrict__ w2t4) {
    const int id = blockIdx.x * 256 + threadIdx.x;      // B*SEG*C = 65536
    if (id < C8 * C) {
        {   // w1
            const int o = id >> 9;        // / C
            const int k = id & (C - 1);
            w1t4[((k >> 2) * C8 + o) * 4 + (k & 3)] = w1[id];
        }
        {   // w2
            const int c = id >> 6;        // / C8
            const int k = id & (C8 - 1);
            w2t4[((k >> 2) * C + c) * 4 + (k & 3)] = w2[id];
        }
    }
    const int c = id & (C - 1);
    const int rest = id >> 9;
    const int s = rest & (SEG - 1);
    const int b = rest >> 4;
    const float g = gamma[c];
    const float omg = 1.0f - g;
    float* p = pool + ((size_t)(b * N + s * SL)) * C + c;
    float y = 0.0f;
#pragma unroll 8
    for (int i = 0; i < SL; ++i) {
        const float xv = p[(size_t)i * C];
        y = fmaf(g, y, omg * xv);
        p[(size_t)i * C] = y;
    }
    carry[(size_t)(b * SEG + s) * C + c] = y;
}

// ---------------------------------------------------------------------------
// Kernel 3: EMA pass B — apply carry prefix.
// start_s = E_{s-1} where E_t = carry_t + g^32 * E_{t-1};
// y_true[base+i] = local[base+i] + g^{i+1} * start_s.
// ---------------------------------------------------------------------------
__global__ __launch_bounds__(256) void emaB_k(const float* __restrict__ gamma,
                                              float* __restrict__ pool,
                                              const float* __restrict__ carry) {
    const int id = blockIdx.x * 256 + threadIdx.x;      // B*SEG*C
    const int c = id & (C - 1);
    const int rest = id >> 9;
    const int s = rest & (SEG - 1);
    const int b = rest >> 4;
    if (s == 0) return;                                  // wave-uniform
    const float g = gamma[c];
    float g32 = g * g;   // g^2
    g32 *= g32;          // g^4
    g32 *= g32;          // g^8
    g32 *= g32;          // g^16
    g32 *= g32;          // g^32
    float E = 0.0f;
    const float* cb = carry + (size_t)b * SEG * C + c;
    for (int t = 0; t < s; ++t)
        E = fmaf(g32, E, cb[(size_t)t * C]);
    float* p = pool + ((size_t)(b * N + s * SL)) * C + c;
    float gp = g;
#pragma unroll 8
    for (int i = 0; i < SL; ++i) {
        p[(size_t)i * C] = fmaf(gp, E, p[(size_t)i * C]);
        gp *= g;
    }
}

// ---------------------------------------------------------------------------
// Kernel 4: SE bottleneck + sigmoid.  e [B,N,C] -> gate [B,N,C].
// One block per 4 chunk-steps; float4-packed weight loads.
// ---------------------------------------------------------------------------
#define NT 4
__global__ __launch_bounds__(256) void se_k(const float* __restrict__ e,
                                            const float* __restrict__ w1t4,
                                            const float* __restrict__ b1,
                                            const float* __restrict__ w2t4,
                                            const float* __restrict__ b2,
                                            float* __restrict__ gate) {
    __shared__ float e_s[NT * C];     // 8 KB
    __shared__ float h_s[NT][C8];     // 1 KB

    const int t = threadIdx.x;
    const int blk = blockIdx.x;                  // B*N/NT blocks
    const int b = blk >> 7;                      // / (N/NT = 128)
    const int n0 = (blk & 127) * NT;
    const float* ebase = e + ((size_t)b * N + n0) * C;

    const float4* e4 = reinterpret_cast<const float4*>(ebase);
#pragma unroll
    for (int i = 0; i < NT * C / 4 / 256; ++i)   // 2 iters
        reinterpret_cast<float4*>(e_s)[i * 256 + t] = e4[i * 256 + t];
    __syncthreads();

    // h[j][o] = relu(b1[o] + sum_k w1[o,k] * e[j,k])
    const int o = t & (C8 - 1);
    const int j = t >> 6;                        // one j per wave -> e_s broadcast
    float acc = b1[o];
    const float4* w1v = reinterpret_cast<const float4*>(w1t4) + o;
    const float* ej = e_s + j * C;
#pragma unroll 8
    for (int k4 = 0; k4 < C / 4; ++k4) {
        const float4 w = w1v[(size_t)k4 * C8];
        acc = fmaf(w.x, ej[4 * k4 + 0], acc);
        acc = fmaf(w.y, ej[4 * k4 + 1], acc);
        acc = fmaf(w.z, ej[4 * k4 + 2], acc);
        acc = fmaf(w.w, ej[4 * k4 + 3], acc);
    }
    h_s[j][o] = fmaxf(acc, 0.0f);
    __syncthreads();

    // gate[j][c] = sigmoid(b2[c] + sum_k w2[c,k] * h[j][k])
    float* gbase = gate + ((size_t)b * N + n0) * C;
#pragma unroll
    for (int r = 0; r < NT * C / 256; ++r) {
        const int idx = r * 256 + t;             // jj*C + c
        const int c = idx & (C - 1);
        const int jj = idx >> 9;
        float a = b2[c];
        const float4* w2v = reinterpret_cast<const float4*>(w2t4) + c;
#pragma unroll
        for (int k4 = 0; k4 < C8 / 4; ++k4) {
            const float4 w = w2v[(size_t)k4 * C];
            a = fmaf(w.x, h_s[jj][4 * k4 + 0], a);
            a = fmaf(w.y, h_s[jj][4 * k4 + 1], a);
            a = fmaf(w.z, h_s[jj][4 * k4 + 2], a);
            a = fmaf(w.w, h_s[jj][4 * k4 + 3], a);
        }
        gbase[idx] = 1.0f / (1.0f + __expf(-a));
    }
}

// ---------------------------------------------------------------------------
// Kernel 5: apply gate.  out[b,c,l] = gate[b, l/16, c] * x[b,c,l]
// ---------------------------------------------------------------------------
__global__ __launch_bounds__(256) void apply_k(const float* __restrict__ x,
                                               const float* __restrict__ gate,
                                               float* __restrict__ out) {
    const size_t id = (size_t)blockIdx.x * 256 + threadIdx.x;   // float4 index
    const int per_row = L / 4;                   // 2048 float4 per (b,c) row
    const int bc = (int)(id / per_row);
    const int wi = (int)(id % per_row);
    const int n = wi >> 2;
    const int c = bc & (C - 1);
    const int b = bc >> 9;

    const float g = gate[((size_t)b * N + n) * C + c];
    float4 v = reinterpret_cast<const float4*>(x)[id];
    v.x *= g; v.y *= g; v.z *= g; v.w *= g;
    reinterpret_cast<float4*>(out)[id] = v;
}

// ---------------------------------------------------------------------------
extern "C" void kernel_launch(void* const* d_in, const int* in_sizes, int n_in,
                              void* d_out, int out_size, void* d_ws, size_t ws_size,
                              hipStream_t stream) {
    const float* x     = (const float*)d_in[0];
    const float* gamma = (const float*)d_in[1];
    const float* w1    = (const float*)d_in[2];
    const float* b1    = (const float*)d_in[3];
    const float* w2    = (const float*)d_in[4];
    const float* b2    = (const float*)d_in[5];
    float* out = (float*)d_out;

    char* ws = (char*)d_ws;
    size_t off = 0;
    float* pool = (float*)(ws + off); off += (size_t)B * N * C * 4;      // 8 MB
    float* gate = (float*)(ws + off); off += (size_t)B * N * C * 4;      // 8 MB
    float* w1t4 = (float*)(ws + off); off += (size_t)C8 * C * 4;         // 128 KB
    float* w2t4 = (float*)(ws + off); off += (size_t)C8 * C * 4;         // 128 KB
    float* carry = (float*)(ws + off); off += (size_t)B * SEG * C * 4;   // 256 KB

    // chunk pooling: x -> pool [B,N,C]
    pool_k<<<(B * C * L / 4) / 256, 256, 0, stream>>>(x, pool);
    // EMA segmented scan pass A (+ weight repack)
    emaA_k<<<(B * SEG * C) / 256, 256, 0, stream>>>(gamma, pool, carry, w1, w2, w1t4, w2t4);
    // EMA pass B: apply carries
    emaB_k<<<(B * SEG * C) / 256, 256, 0, stream>>>(gamma, pool, carry);
    // SE bottleneck -> gate
    se_k<<<(B * N) / NT, 256, 0, stream>>>(pool, w1t4, b1, w2t4, b2, gate);
    // apply gate
    apply_k<<<(B * C * L / 4) / 256, 256, 0, stream>>>(x, gate, out);
}

// Round 3
// 98.399 us; speedup vs baseline: 1.6617x; 1.6617x over previous
//
#include <hip/hip_runtime.h>
#include <math.h>

#define B 8
#define C 512
#define L 8192
#define CS 16
#define N 512      // L/CS chunk steps
#define C8 64      // C/8 bottleneck dim
#define SEG 16     // EMA scan segments per row
#define SL 32      // N/SEG steps per segment
#define ROWS 4096  // B*N total chunk rows

// ---------------------------------------------------------------------------
// Kernel 1: chunked average pooling.  x [B,C,L] -> pool [B,N,C]
// ---------------------------------------------------------------------------
__global__ __launch_bounds__(256) void pool_k(const float* __restrict__ x,
                                              float* __restrict__ pool) {
    const int id = blockIdx.x * 256 + threadIdx.x;      // B*C*L/4 threads
    const int q = id & 3;
    const int chunk = id >> 2;                          // (b*C + c)*N + n
    const int n = chunk & (N - 1);
    const int bc = chunk >> 9;
    const int c = bc & (C - 1);
    const int b = bc >> 9;

    const float4 v = reinterpret_cast<const float4*>(x)[id];
    float s = v.x + v.y + v.z + v.w;
    s += __shfl_down(s, 1, 4);
    s += __shfl_down(s, 2, 4);
    if (q == 0) {
        pool[((size_t)b * N + n) * C + c] = s * (1.0f / 16.0f);
    }
}

// ---------------------------------------------------------------------------
// Kernel 2: EMA pass A — segment-local scans + per-segment carry.
// Also folds in the tiny weight re-pack for the SE matvecs.
// ---------------------------------------------------------------------------
__global__ __launch_bounds__(256) void emaA_k(const float* __restrict__ gamma,
                                              float* __restrict__ pool,
                                              float* __restrict__ carry,
                                              const float* __restrict__ w1,
                                              const float* __restrict__ w2,
                                              float* __restrict__ w1t4,
                                              float* __restrict__ w2t4) {
    const int id = blockIdx.x * 256 + threadIdx.x;      // B*SEG*C = 65536
    if (id < C8 * C) {
        {   // w1 [C8][C] -> float4-interleaved [(k/4)*C8 + o][4]
            const int o = id >> 9;
            const int k = id & (C - 1);
            w1t4[((k >> 2) * C8 + o) * 4 + (k & 3)] = w1[id];
        }
        {   // w2 [C][C8] -> float4-interleaved [(k/4)*C + c][4]
            const int c = id >> 6;
            const int k = id & (C8 - 1);
            w2t4[((k >> 2) * C + c) * 4 + (k & 3)] = w2[id];
        }
    }
    const int c = id & (C - 1);
    const int rest = id >> 9;
    const int s = rest & (SEG - 1);
    const int b = rest >> 4;
    const float g = gamma[c];
    const float omg = 1.0f - g;
    float* p = pool + ((size_t)(b * N + s * SL)) * C + c;
    float y = 0.0f;
#pragma unroll 8
    for (int i = 0; i < SL; ++i) {
        const float xv = p[(size_t)i * C];
        y = fmaf(g, y, omg * xv);
        p[(size_t)i * C] = y;
    }
    carry[(size_t)(b * SEG + s) * C + c] = y;
}

// ---------------------------------------------------------------------------
// Kernel 3: EMA pass B — apply carry prefix.
// ---------------------------------------------------------------------------
__global__ __launch_bounds__(256) void emaB_k(const float* __restrict__ gamma,
                                              float* __restrict__ pool,
                                              const float* __restrict__ carry) {
    const int id = blockIdx.x * 256 + threadIdx.x;      // B*SEG*C
    const int c = id & (C - 1);
    const int rest = id >> 9;
    const int s = rest & (SEG - 1);
    const int b = rest >> 4;
    if (s == 0) return;                                  // wave-uniform
    const float g = gamma[c];
    float g32 = g * g;
    g32 *= g32; g32 *= g32; g32 *= g32; g32 *= g32;      // g^32
    float E = 0.0f;
    const float* cb = carry + (size_t)b * SEG * C + c;
    for (int t = 0; t < s; ++t)
        E = fmaf(g32, E, cb[(size_t)t * C]);
    float* p = pool + ((size_t)(b * N + s * SL)) * C + c;
    float gp = g;
#pragma unroll 8
    for (int i = 0; i < SL; ++i) {
        p[(size_t)i * C] = fmaf(gp, E, p[(size_t)i * C]);
        gp *= g;
    }
}

// ---------------------------------------------------------------------------
// Kernel 4: SE GEMM1 partials.  e [ROWS][C] x w1t4 -> ph[ks][ROWS][C8]
// Grid: 128 row-blocks x 2 k-halves.  Block: 256 thr = 32 o-pairs x 8 jg.
// Per thread: 2 o-cols x 4 rows register tile -> 32 fma per (2 w-load + 4 LDS).
// ---------------------------------------------------------------------------
__global__ __launch_bounds__(256) void se1_k(const float* __restrict__ e,
                                             const float* __restrict__ w1t4,
                                             float* __restrict__ ph) {
    __shared__ float e_s[32 * 256];   // 32KB: [row_local][k_half]
    const int t = threadIdx.x;
    const int rb = blockIdx.x >> 1;
    const int ks = blockIdx.x & 1;
    const int row0 = rb * 32;

    // stage 32 rows x 256 k (2048 float4, 8/thread), coalesced
#pragma unroll
    for (int i = 0; i < 8; ++i) {
        const int idx = i * 256 + t;        // 0..2047
        const int r = idx >> 6;             // 64 float4 per row
        const int kk = idx & 63;
        reinterpret_cast<float4*>(e_s)[idx] =
            reinterpret_cast<const float4*>(e + (size_t)(row0 + r) * C + ks * 256)[kk];
    }
    __syncthreads();

    const int oc = t & 31;
    const int jg = t >> 5;                  // 0..7 -> rows jg*4..+3
    float a0[4] = {0.f, 0.f, 0.f, 0.f};
    float a1[4] = {0.f, 0.f, 0.f, 0.f};
    const float4* w1v = reinterpret_cast<const float4*>(w1t4);
    const float4* es4 = reinterpret_cast<const float4*>(e_s);
#pragma unroll 4
    for (int k4 = 0; k4 < 64; ++k4) {
        const float4 wa = w1v[(size_t)(ks * 64 + k4) * C8 + oc];
        const float4 wb = w1v[(size_t)(ks * 64 + k4) * C8 + oc + 32];
#pragma unroll
        for (int r = 0; r < 4; ++r) {
            const float4 ev = es4[(jg * 4 + r) * 64 + k4];
            a0[r] = fmaf(wa.x, ev.x, a0[r]); a0[r] = fmaf(wa.y, ev.y, a0[r]);
            a0[r] = fmaf(wa.z, ev.z, a0[r]); a0[r] = fmaf(wa.w, ev.w, a0[r]);
            a1[r] = fmaf(wb.x, ev.x, a1[r]); a1[r] = fmaf(wb.y, ev.y, a1[r]);
            a1[r] = fmaf(wb.z, ev.z, a1[r]); a1[r] = fmaf(wb.w, ev.w, a1[r]);
        }
    }
    float* pbase = ph + ((size_t)ks * ROWS + row0) * C8;
#pragma unroll
    for (int r = 0; r < 4; ++r) {
        pbase[(size_t)(jg * 4 + r) * C8 + oc]      = a0[r];
        pbase[(size_t)(jg * 4 + r) * C8 + oc + 32] = a1[r];
    }
}

// ---------------------------------------------------------------------------
// Kernel 5: SE GEMM2.  h = relu(b1 + ph0 + ph1); gate = sigmoid(h w2^T + b2)
// Grid: 128 row-blocks x 4 col-tiles.  Block: 256 thr = 64 c-lanes x 4 jg.
// Per thread: 2 c-cols x 8 rows -> 8:1 fma:LDS-b128 ratio.
// ---------------------------------------------------------------------------
__global__ __launch_bounds__(256) void se2_k(const float* __restrict__ ph,
                                             const float* __restrict__ b1,
                                             const float* __restrict__ w2t4,
                                             const float* __restrict__ b2,
                                             float* __restrict__ gate) {
    __shared__ float h_s[32 * C8];   // 8KB [row_local][o]
    const int t = threadIdx.x;
    const int rb = blockIdx.x >> 2;
    const int ct = blockIdx.x & 3;
    const int row0 = rb * 32;

    // stage h = relu(b1 + ph0 + ph1): 512 float4, 2/thread
    {
        const float4* p0 = reinterpret_cast<const float4*>(ph + (size_t)row0 * C8);
        const float4* p1 = reinterpret_cast<const float4*>(ph + (size_t)(ROWS + row0) * C8);
        const float4* b1v = reinterpret_cast<const float4*>(b1);
#pragma unroll
        for (int i = 0; i < 2; ++i) {
            const int idx = i * 256 + t;     // row = idx>>4, o4 = idx&15
            const float4 u = p0[idx];
            const float4 v = p1[idx];
            const float4 bb = b1v[idx & 15];
            float4 hv;
            hv.x = fmaxf(bb.x + u.x + v.x, 0.f);
            hv.y = fmaxf(bb.y + u.y + v.y, 0.f);
            hv.z = fmaxf(bb.z + u.z + v.z, 0.f);
            hv.w = fmaxf(bb.w + u.w + v.w, 0.f);
            reinterpret_cast<float4*>(h_s)[idx] = hv;
        }
    }
    __syncthreads();

    const int cl = t & 63;
    const int jg = t >> 6;                  // rows jg*8..+7
    const int c = ct * 128 + cl;
    float acc0[8], acc1[8];
    const float bb0 = b2[c];
    const float bb1 = b2[c + 64];
#pragma unroll
    for (int j = 0; j < 8; ++j) { acc0[j] = bb0; acc1[j] = bb1; }
    const float4* w2v = reinterpret_cast<const float4*>(w2t4);
    const float4* hs4 = reinterpret_cast<const float4*>(h_s);
#pragma unroll
    for (int k4 = 0; k4 < 16; ++k4) {
        const float4 wa = w2v[(size_t)k4 * C + c];
        const float4 wb = w2v[(size_t)k4 * C + c + 64];
#pragma unroll
        for (int j = 0; j < 8; ++j) {
            const float4 hv = hs4[(jg * 8 + j) * 16 + k4];
            acc0[j] = fmaf(wa.x, hv.x, acc0[j]); acc0[j] = fmaf(wa.y, hv.y, acc0[j]);
            acc0[j] = fmaf(wa.z, hv.z, acc0[j]); acc0[j] = fmaf(wa.w, hv.w, acc0[j]);
            acc1[j] = fmaf(wb.x, hv.x, acc1[j]); acc1[j] = fmaf(wb.y, hv.y, acc1[j]);
            acc1[j] = fmaf(wb.z, hv.z, acc1[j]); acc1[j] = fmaf(wb.w, hv.w, acc1[j]);
        }
    }
    float* gbase = gate + (size_t)row0 * C;
#pragma unroll
    for (int j = 0; j < 8; ++j) {
        const int r = jg * 8 + j;
        gbase[(size_t)r * C + c]      = 1.0f / (1.0f + __expf(-acc0[j]));
        gbase[(size_t)r * C + c + 64] = 1.0f / (1.0f + __expf(-acc1[j]));
    }
}

// ---------------------------------------------------------------------------
// Kernel 6: apply gate.  out[b,c,l] = gate[b, l/16, c] * x[b,c,l]
// ---------------------------------------------------------------------------
__global__ __launch_bounds__(256) void apply_k(const float* __restrict__ x,
                                               const float* __restrict__ gate,
                                               float* __restrict__ out) {
    const size_t id = (size_t)blockIdx.x * 256 + threadIdx.x;   // float4 index
    const int per_row = L / 4;                   // 2048 float4 per (b,c) row
    const int bc = (int)(id / per_row);
    const int wi = (int)(id % per_row);
    const int n = wi >> 2;
    const int c = bc & (C - 1);
    const int b = bc >> 9;

    const float g = gate[((size_t)b * N + n) * C + c];
    float4 v = reinterpret_cast<const float4*>(x)[id];
    v.x *= g; v.y *= g; v.z *= g; v.w *= g;
    reinterpret_cast<float4*>(out)[id] = v;
}

// ---------------------------------------------------------------------------
extern "C" void kernel_launch(void* const* d_in, const int* in_sizes, int n_in,
                              void* d_out, int out_size, void* d_ws, size_t ws_size,
                              hipStream_t stream) {
    const float* x     = (const float*)d_in[0];
    const float* gamma = (const float*)d_in[1];
    const float* w1    = (const float*)d_in[2];
    const float* b1    = (const float*)d_in[3];
    const float* w2    = (const float*)d_in[4];
    const float* b2    = (const float*)d_in[5];
    float* out = (float*)d_out;

    char* ws = (char*)d_ws;
    size_t off = 0;
    float* pool  = (float*)(ws + off); off += (size_t)B * N * C * 4;      // 8 MB
    float* gate  = (float*)(ws + off); off += (size_t)B * N * C * 4;      // 8 MB
    float* w1t4  = (float*)(ws + off); off += (size_t)C8 * C * 4;         // 128 KB
    float* w2t4  = (float*)(ws + off); off += (size_t)C8 * C * 4;         // 128 KB
    float* carry = (float*)(ws + off); off += (size_t)B * SEG * C * 4;    // 256 KB
    float* ph    = (float*)(ws + off); off += (size_t)2 * ROWS * C8 * 4;  // 2 MB

    // chunk pooling: x -> pool [B,N,C]
    pool_k<<<(B * C * L / 4) / 256, 256, 0, stream>>>(x, pool);
    // EMA segmented scan pass A (+ weight repack)
    emaA_k<<<(B * SEG * C) / 256, 256, 0, stream>>>(gamma, pool, carry, w1, w2, w1t4, w2t4);
    // EMA pass B: apply carries
    emaB_k<<<(B * SEG * C) / 256, 256, 0, stream>>>(gamma, pool, carry);
    // SE GEMM1 partials (k-split 2)
    se1_k<<<128 * 2, 256, 0, stream>>>(pool, w1t4, ph);
    // SE GEMM2: combine + bias/relu, x w2^T, sigmoid -> gate
    se2_k<<<128 * 4, 256, 0, stream>>>(ph, b1, w2t4, b2, gate);
    // apply gate
    apply_k<<<(B * C * L / 4) / 256, 256, 0, stream>>>(x, gate, out);
}

// Round 4
// 96.911 us; speedup vs baseline: 1.6872x; 1.0154x over previous
//
#include <hip/hip_runtime.h>
#include <math.h>

#define B 8
#define C 512
#define L 8192
#define CS 16
#define N 512      // L/CS chunk steps
#define C8 64      // C/8 bottleneck dim
#define SEG 16     // EMA scan segments per row
#define SL 32      // N/SEG steps per segment
#define ROWS 4096  // B*N total chunk rows

// ---------------------------------------------------------------------------
// Kernel 1: chunked average pooling.  x [B,C,L] -> pool [B,N,C]
// Block = one (b, 16c, 16n) tile. Reads: each wave streams one 1 KB
// contiguous row. LDS-transpose so writes are 64 B-contiguous in c.
// ---------------------------------------------------------------------------
__global__ __launch_bounds__(256) void pool_k(const float* __restrict__ x,
                                              float* __restrict__ pool) {
    __shared__ float tile[16][17];          // +1 pad: conflict-free transpose
    const int t = threadIdx.x;
    const int bid = blockIdx.x;             // B * 32 * 32 = 8192
    const int nt = bid & 31;
    const int ct = (bid >> 5) & 31;
    const int b  = bid >> 10;
    const int w    = t >> 6;                // wave 0..3
    const int lane = t & 63;

#pragma unroll
    for (int i = 0; i < 4; ++i) {
        const int c_local = i * 4 + w;
        const int c = ct * 16 + c_local;
        const float4 v = reinterpret_cast<const float4*>(x)[
            (size_t)(b * C + c) * (L / 4) + nt * 64 + lane];
        float s = v.x + v.y + v.z + v.w;
        s += __shfl_down(s, 1, 4);
        s += __shfl_down(s, 2, 4);
        if ((lane & 3) == 0)
            tile[c_local][lane >> 2] = s * (1.0f / 16.0f);
    }
    __syncthreads();

    const int n_local = t >> 4;
    const int c_local = t & 15;
    pool[(size_t)(b * N + nt * 16 + n_local) * C + ct * 16 + c_local] =
        tile[c_local][n_local];
}

// ---------------------------------------------------------------------------
// Kernel 2: EMA carries only (segment-local scan endpoint per (b,s,c)).
// pool is NOT modified. Also folds in the tiny weight re-pack.
// ---------------------------------------------------------------------------
__global__ __launch_bounds__(256) void emaA_k(const float* __restrict__ gamma,
                                              const float* __restrict__ pool,
                                              float* __restrict__ carry,
                                              const float* __restrict__ w1,
                                              const float* __restrict__ w2,
                                              float* __restrict__ w1t4,
                                              float* __restrict__ w2t4) {
    const int id = blockIdx.x * 256 + threadIdx.x;      // B*SEG*C = 65536
    if (id < C8 * C) {
        {   // w1 [C8][C] -> float4-interleaved [(k/4)*C8 + o][4]
            const int o = id >> 9;
            const int k = id & (C - 1);
            w1t4[((k >> 2) * C8 + o) * 4 + (k & 3)] = w1[id];
        }
        {   // w2 [C][C8] -> float4-interleaved [(k/4)*C + c][4]
            const int c = id >> 6;
            const int k = id & (C8 - 1);
            w2t4[((k >> 2) * C + c) * 4 + (k & 3)] = w2[id];
        }
    }
    const int c = id & (C - 1);
    const int rest = id >> 9;
    const int s = rest & (SEG - 1);
    const int b = rest >> 4;
    const float g = gamma[c];
    const float omg = 1.0f - g;
    const float* p = pool + ((size_t)(b * N + s * SL)) * C + c;
    float y = 0.0f;
#pragma unroll 8
    for (int i = 0; i < SL; ++i)
        y = fmaf(g, y, omg * p[(size_t)i * C]);
    carry[(size_t)(b * SEG + s) * C + c] = y;
}

// ---------------------------------------------------------------------------
// Kernel 3: SE GEMM1 with fused EMA finish.
// Block (rb, ks): rows rb*32..+31 = segment (b = rb/16, s = rb%16).
// Stage raw pool half-k, seed scan with E_{s-1} from carries (EMA linearity),
// scan 32 rows in LDS, then register-tiled GEMM -> ph[ks][ROWS][C8].
// ---------------------------------------------------------------------------
__global__ __launch_bounds__(256) void se1_k(const float* __restrict__ pool,
                                             const float* __restrict__ carry,
                                             const float* __restrict__ gamma,
                                             const float* __restrict__ w1t4,
                                             float* __restrict__ ph) {
    __shared__ float e_s[32 * 256];   // 32KB: [row_local][k_half]
    const int t = threadIdx.x;
    const int rb = blockIdx.x >> 1;
    const int ks = blockIdx.x & 1;
    const int b = rb >> 4;
    const int s = rb & 15;
    const int row0 = rb * 32;

    // stage 32 rows x 256 k (2048 float4, 8/thread), coalesced
#pragma unroll
    for (int i = 0; i < 8; ++i) {
        const int idx = i * 256 + t;        // 0..2047
        const int r = idx >> 6;             // 64 float4 per row-half
        const int kk = idx & 63;
        reinterpret_cast<float4*>(e_s)[idx] =
            reinterpret_cast<const float4*>(pool + (size_t)(row0 + r) * C + ks * 256)[kk];
    }
    __syncthreads();

    // EMA finish: thread t = local channel; c = ks*256 + t.
    {
        const int c = ks * 256 + t;
        const float g = gamma[c];
        const float omg = 1.0f - g;
        float g32 = g * g;
        g32 *= g32; g32 *= g32; g32 *= g32; g32 *= g32;   // g^32
        float E = 0.0f;
        const float* cb = carry + (size_t)b * SEG * C + c;
        for (int tt = 0; tt < s; ++tt)
            E = fmaf(g32, E, cb[(size_t)tt * C]);
        float y = E;                       // state entering this segment
#pragma unroll
        for (int r = 0; r < 32; ++r) {
            y = fmaf(g, y, omg * e_s[r * 256 + t]);
            e_s[r * 256 + t] = y;
        }
    }
    __syncthreads();

    const int oc = t & 31;
    const int jg = t >> 5;                  // rows jg*4..+3
    float a0[4] = {0.f, 0.f, 0.f, 0.f};
    float a1[4] = {0.f, 0.f, 0.f, 0.f};
    const float4* w1v = reinterpret_cast<const float4*>(w1t4);
    const float4* es4 = reinterpret_cast<const float4*>(e_s);
#pragma unroll 4
    for (int k4 = 0; k4 < 64; ++k4) {
        const float4 wa = w1v[(size_t)(ks * 64 + k4) * C8 + oc];
        const float4 wb = w1v[(size_t)(ks * 64 + k4) * C8 + oc + 32];
#pragma unroll
        for (int r = 0; r < 4; ++r) {
            const float4 ev = es4[(jg * 4 + r) * 64 + k4];
            a0[r] = fmaf(wa.x, ev.x, a0[r]); a0[r] = fmaf(wa.y, ev.y, a0[r]);
            a0[r] = fmaf(wa.z, ev.z, a0[r]); a0[r] = fmaf(wa.w, ev.w, a0[r]);
            a1[r] = fmaf(wb.x, ev.x, a1[r]); a1[r] = fmaf(wb.y, ev.y, a1[r]);
            a1[r] = fmaf(wb.z, ev.z, a1[r]); a1[r] = fmaf(wb.w, ev.w, a1[r]);
        }
    }
    float* pbase = ph + ((size_t)ks * ROWS + row0) * C8;
#pragma unroll
    for (int r = 0; r < 4; ++r) {
        pbase[(size_t)(jg * 4 + r) * C8 + oc]      = a0[r];
        pbase[(size_t)(jg * 4 + r) * C8 + oc + 32] = a1[r];
    }
}

// ---------------------------------------------------------------------------
// Kernel 4: SE GEMM2.  h = relu(b1 + ph0 + ph1); gate = sigmoid(h w2^T + b2)
// Output layout TRANSPOSED to [B,C,N]: each thread owns 8 consecutive n per
// column -> two float4 register stores (32 B aligned); full 128 B lines are
// completed by the 4 waves of the same block -> coalesces in L2.
// ---------------------------------------------------------------------------
__global__ __launch_bounds__(256) void se2_k(const float* __restrict__ ph,
                                             const float* __restrict__ b1,
                                             const float* __restrict__ w2t4,
                                             const float* __restrict__ b2,
                                             float* __restrict__ gate) {
    __shared__ float h_s[32 * C8];   // 8KB [row_local][o]
    const int t = threadIdx.x;
    const int rb = blockIdx.x >> 2;
    const int ct = blockIdx.x & 3;
    const int row0 = rb * 32;
    const int b = rb >> 4;
    const int n0 = (rb & 15) * 32;

    // stage h = relu(b1 + ph0 + ph1): 512 float4, 2/thread
    {
        const float4* p0 = reinterpret_cast<const float4*>(ph + (size_t)row0 * C8);
        const float4* p1 = reinterpret_cast<const float4*>(ph + (size_t)(ROWS + row0) * C8);
        const float4* b1v = reinterpret_cast<const float4*>(b1);
#pragma unroll
        for (int i = 0; i < 2; ++i) {
            const int idx = i * 256 + t;
            const float4 u = p0[idx];
            const float4 v = p1[idx];
            const float4 bb = b1v[idx & 15];
            float4 hv;
            hv.x = fmaxf(bb.x + u.x + v.x, 0.f);
            hv.y = fmaxf(bb.y + u.y + v.y, 0.f);
            hv.z = fmaxf(bb.z + u.z + v.z, 0.f);
            hv.w = fmaxf(bb.w + u.w + v.w, 0.f);
            reinterpret_cast<float4*>(h_s)[idx] = hv;
        }
    }
    __syncthreads();

    const int cl = t & 63;
    const int jg = t >> 6;                  // rows (n) jg*8..+7
    const int c = ct * 128 + cl;
    float acc0[8], acc1[8];
    const float bb0 = b2[c];
    const float bb1 = b2[c + 64];
#pragma unroll
    for (int j = 0; j < 8; ++j) { acc0[j] = bb0; acc1[j] = bb1; }
    const float4* w2v = reinterpret_cast<const float4*>(w2t4);
    const float4* hs4 = reinterpret_cast<const float4*>(h_s);
#pragma unroll
    for (int k4 = 0; k4 < 16; ++k4) {
        const float4 wa = w2v[(size_t)k4 * C + c];
        const float4 wb = w2v[(size_t)k4 * C + c + 64];
#pragma unroll
        for (int j = 0; j < 8; ++j) {
            const float4 hv = hs4[(jg * 8 + j) * 16 + k4];
            acc0[j] = fmaf(wa.x, hv.x, acc0[j]); acc0[j] = fmaf(wa.y, hv.y, acc0[j]);
            acc0[j] = fmaf(wa.z, hv.z, acc0[j]); acc0[j] = fmaf(wa.w, hv.w, acc0[j]);
            acc1[j] = fmaf(wb.x, hv.x, acc1[j]); acc1[j] = fmaf(wb.y, hv.y, acc1[j]);
            acc1[j] = fmaf(wb.z, hv.z, acc1[j]); acc1[j] = fmaf(wb.w, hv.w, acc1[j]);
        }
    }
    // gate [B,C,N]: 8 consecutive n per column per thread
    {
        float4 o0, o1;
        float* g0 = gate + ((size_t)(b * C + c)) * N + n0 + jg * 8;
        float* g1 = gate + ((size_t)(b * C + c + 64)) * N + n0 + jg * 8;
        o0.x = 1.0f / (1.0f + __expf(-acc0[0]));
        o0.y = 1.0f / (1.0f + __expf(-acc0[1]));
        o0.z = 1.0f / (1.0f + __expf(-acc0[2]));
        o0.w = 1.0f / (1.0f + __expf(-acc0[3]));
        o1.x = 1.0f / (1.0f + __expf(-acc0[4]));
        o1.y = 1.0f / (1.0f + __expf(-acc0[5]));
        o1.z = 1.0f / (1.0f + __expf(-acc0[6]));
        o1.w = 1.0f / (1.0f + __expf(-acc0[7]));
        reinterpret_cast<float4*>(g0)[0] = o0;
        reinterpret_cast<float4*>(g0)[1] = o1;
        o0.x = 1.0f / (1.0f + __expf(-acc1[0]));
        o0.y = 1.0f / (1.0f + __expf(-acc1[1]));
        o0.z = 1.0f / (1.0f + __expf(-acc1[2]));
        o0.w = 1.0f / (1.0f + __expf(-acc1[3]));
        o1.x = 1.0f / (1.0f + __expf(-acc1[4]));
        o1.y = 1.0f / (1.0f + __expf(-acc1[5]));
        o1.z = 1.0f / (1.0f + __expf(-acc1[6]));
        o1.w = 1.0f / (1.0f + __expf(-acc1[7]));
        reinterpret_cast<float4*>(g1)[0] = o0;
        reinterpret_cast<float4*>(g1)[1] = o1;
    }
}

// ---------------------------------------------------------------------------
// Kernel 5: apply gate.  out[b,c,l] = gate[b,c,l/16] * x[b,c,l]
// gate now [B,C,N]: wave reads 16 consecutive n (64 B line, quad-broadcast).
// ---------------------------------------------------------------------------
__global__ __launch_bounds__(256) void apply_k(const float* __restrict__ x,
                                               const float* __restrict__ gate,
                                               float* __restrict__ out) {
    const size_t id = (size_t)blockIdx.x * 256 + threadIdx.x;   // float4 index
    const int per_row = L / 4;                   // 2048 float4 per (b,c) row
    const int bc = (int)(id / per_row);
    const int wi = (int)(id % per_row);
    const int n = wi >> 2;

    const float g = gate[(size_t)bc * N + n];
    float4 v = reinterpret_cast<const float4*>(x)[id];
    v.x *= g; v.y *= g; v.z *= g; v.w *= g;
    reinterpret_cast<float4*>(out)[id] = v;
}

// ---------------------------------------------------------------------------
extern "C" void kernel_launch(void* const* d_in, const int* in_sizes, int n_in,
                              void* d_out, int out_size, void* d_ws, size_t ws_size,
                              hipStream_t stream) {
    const float* x     = (const float*)d_in[0];
    const float* gamma = (const float*)d_in[1];
    const float* w1    = (const float*)d_in[2];
    const float* b1    = (const float*)d_in[3];
    const float* w2    = (const float*)d_in[4];
    const float* b2    = (const float*)d_in[5];
    float* out = (float*)d_out;

    char* ws = (char*)d_ws;
    size_t off = 0;
    float* pool  = (float*)(ws + off); off += (size_t)B * N * C * 4;      // 8 MB
    float* gate  = (float*)(ws + off); off += (size_t)B * N * C * 4;      // 8 MB
    float* w1t4  = (float*)(ws + off); off += (size_t)C8 * C * 4;         // 128 KB
    float* w2t4  = (float*)(ws + off); off += (size_t)C8 * C * 4;         // 128 KB
    float* carry = (float*)(ws + off); off += (size_t)B * SEG * C * 4;    // 256 KB
    float* ph    = (float*)(ws + off); off += (size_t)2 * ROWS * C8 * 4;  // 2 MB

    // chunk pooling: x -> pool [B,N,C] (tiled, coalesced both sides)
    pool_k<<<B * 32 * 32, 256, 0, stream>>>(x, pool);
    // EMA segment carries (+ weight repack); pool left untouched
    emaA_k<<<(B * SEG * C) / 256, 256, 0, stream>>>(gamma, pool, carry, w1, w2, w1t4, w2t4);
    // SE GEMM1 with fused EMA finish (k-split 2)
    se1_k<<<128 * 2, 256, 0, stream>>>(pool, carry, gamma, w1t4, ph);
    // SE GEMM2 -> gate [B,C,N]
    se2_k<<<128 * 4, 256, 0, stream>>>(ph, b1, w2t4, b2, gate);
    // apply gate
    apply_k<<<(B * C * L / 4) / 256, 256, 0, stream>>>(x, gate, out);
}